// Round 1
// baseline (1232.458 us; speedup 1.0000x reference)
//
#include <hip/hip_runtime.h>
#include <cstdint>
#include <cstddef>

typedef unsigned short u16;
typedef short short8 __attribute__((ext_vector_type(8)));
typedef float f32x4 __attribute__((ext_vector_type(4)));

__device__ __forceinline__ u16 f2bf(float f) {
  unsigned u = __float_as_uint(f);
  u += 0x7fffu + ((u >> 16) & 1u);
  return (u16)(u >> 16);
}
__device__ __forceinline__ float bf2f(u16 h) {
  return __uint_as_float(((unsigned)h) << 16);
}

typedef const __attribute__((address_space(1))) unsigned int gu32_t;
typedef __attribute__((address_space(3))) unsigned int su32_t;
__device__ __forceinline__ void gl2lds16(const void* g, void* l) {
  __builtin_amdgcn_global_load_lds((gu32_t*)g, (su32_t*)l, 16, 0, 0);
}

__device__ __forceinline__ f32x4 mfma_bf16(short8 a, short8 b, f32x4 c) {
  return __builtin_amdgcn_mfma_f32_16x16x32_bf16(a, b, c, 0, 0, 0);
}

// ---------------- elementwise fp32 -> bf16 ----------------
__global__ __launch_bounds__(256) void f32_to_bf16_kernel(
    const float* __restrict__ x, u16* __restrict__ y, int n) {
  int i = (blockIdx.x * 256 + threadIdx.x) * 4;
  if (i + 3 < n) {
    float4 v = *(const float4*)(x + i);
    ushort4 o;
    o.x = f2bf(v.x); o.y = f2bf(v.y); o.z = f2bf(v.z); o.w = f2bf(v.w);
    *(ushort4*)(y + i) = o;
  }
}

// ---------------- W [K][N] fp32 -> Wt [N][K] bf16 (tiled transpose) ----------------
__global__ __launch_bounds__(256) void transpose_w_kernel(
    const float* __restrict__ W, u16* __restrict__ Wt, int K, int N) {
  __shared__ float tile[32][33];
  int n0 = blockIdx.x * 32, k0 = blockIdx.y * 32;
  int tx = threadIdx.x, ty = threadIdx.y;
#pragma unroll
  for (int j = 0; j < 4; ++j)
    tile[ty + j * 8][tx] = W[(size_t)(k0 + ty + j * 8) * N + n0 + tx];
  __syncthreads();
#pragma unroll
  for (int j = 0; j < 4; ++j)
    Wt[(size_t)(n0 + ty + j * 8) * K + k0 + tx] = f2bf(tile[tx][ty + j * 8]);
}

// ---------------- GEMM: C[M][ldc] = A[M][K] @ Bt[N][K]^T  (bf16 in, fp32 acc) ----------------
template <bool BF16OUT>
__global__ __launch_bounds__(256) void gemm_bt(
    const u16* __restrict__ A, const u16* __restrict__ Bt,
    float* __restrict__ Cf, u16* __restrict__ Cb, int K, int ldc) {
  __shared__ alignas(16) u16 As[128 * 32];
  __shared__ alignas(16) u16 Bs[128 * 32];
  const int tid = threadIdx.x;
  const int w = tid >> 6, lane = tid & 63;
  const int lq = lane & 15, qd = lane >> 4;
  const int wm = w >> 1, wn = w & 1;
  const int m0 = blockIdx.y * 128, n0 = blockIdx.x * 128;
  const int r4 = lane >> 2, c8 = (lane & 3) * 8;

  f32x4 acc[4][4] = {};

  const u16* ap = A + ((size_t)(m0 + w * 16 + r4) * K + c8);
  const u16* bp = Bt + ((size_t)(n0 + w * 16 + r4) * K + c8);
  u16* asd0 = &As[(w * 16) * 32];
  u16* asd1 = &As[(64 + w * 16) * 32];
  u16* bsd0 = &Bs[(w * 16) * 32];
  u16* bsd1 = &Bs[(64 + w * 16) * 32];

  for (int k0 = 0; k0 < K; k0 += 32) {
    gl2lds16(ap + k0, asd0);
    gl2lds16(ap + (size_t)64 * K + k0, asd1);
    gl2lds16(bp + k0, bsd0);
    gl2lds16(bp + (size_t)64 * K + k0, bsd1);
    __syncthreads();
    short8 af[4], bf[4];
#pragma unroll
    for (int i = 0; i < 4; ++i)
      af[i] = *(const short8*)&As[(wm * 64 + i * 16 + lq) * 32 + qd * 8];
#pragma unroll
    for (int j = 0; j < 4; ++j)
      bf[j] = *(const short8*)&Bs[(wn * 64 + j * 16 + lq) * 32 + qd * 8];
#pragma unroll
    for (int i = 0; i < 4; ++i)
#pragma unroll
      for (int j = 0; j < 4; ++j)
        acc[i][j] = mfma_bf16(af[i], bf[j], acc[i][j]);
    __syncthreads();
  }

#pragma unroll
  for (int i = 0; i < 4; ++i) {
    const int row = m0 + wm * 64 + i * 16 + qd * 4;
#pragma unroll
    for (int j = 0; j < 4; ++j) {
      const int col = n0 + wn * 64 + j * 16 + lq;
#pragma unroll
      for (int r = 0; r < 4; ++r) {
        if (BF16OUT)
          Cb[(size_t)(row + r) * ldc + col] = f2bf(acc[i][j][r]);
        else
          Cf[(size_t)(row + r) * ldc + col] = acc[i][j][r];
      }
    }
  }
}

// ---------------- RoPE: qkv_bf slice -> rotated bf16 dst ----------------
// src: [4096][6144] bf16; dst: [4096][nh*128]; pos_ids int32 [4096]
__global__ __launch_bounds__(256) void rope_kernel(
    const u16* __restrict__ src, u16* __restrict__ dst,
    const int* __restrict__ pos_ids, int nh, int src_col0, int dst_ld, int total) {
  int idx = blockIdx.x * 256 + threadIdx.x;
  if (idx >= total) return;
  int i = idx & 63;
  int t = idx >> 6;  // m*nh + hh
  int hh = t % nh;
  int m = t / nh;
  float pos = (float)pos_ids[m];
  // inv_freq[i] = 10000^(-i/64) = 2^(-i*log2(10000)/64)
  float inv = exp2f(-(float)i * 0.20762050593046016f);
  float f = pos * inv;
  float c = cosf(f), s = sinf(f);
  const u16* sp = src + (size_t)m * 6144 + src_col0 + hh * 128;
  float x0 = bf2f(sp[i]);
  float x1 = bf2f(sp[i + 64]);
  u16* dp = dst + (size_t)m * dst_ld + hh * 128;
  dp[i] = f2bf(x0 * c - x1 * s);
  dp[i + 64] = f2bf(x1 * c + x0 * s);
}

// ---------------- V transpose: qkv_bf[.,5120+kvh*128+d] -> Vt[b][kvh][d][s] ----------------
__global__ __launch_bounds__(256) void vt_kernel(
    const u16* __restrict__ src, u16* __restrict__ vt) {
  __shared__ u16 tile[32][33];
  int s0 = blockIdx.x * 32;          // seq tile
  int d0 = blockIdx.y * 32;          // head-dim tile
  int bz = blockIdx.z;               // b*8 + kvh
  int b = bz >> 3, kvh = bz & 7;
  int tx = threadIdx.x, ty = threadIdx.y;
#pragma unroll
  for (int j = 0; j < 4; ++j)
    tile[ty + j * 8][tx] =
        src[(size_t)(b * 2048 + s0 + ty + j * 8) * 6144 + 5120 + kvh * 128 + d0 + tx];
  __syncthreads();
#pragma unroll
  for (int j = 0; j < 4; ++j)
    vt[((size_t)(b * 8 + kvh) * 128 + d0 + ty + j * 8) * 2048 + s0 + tx] =
        tile[tx][ty + j * 8];
}

// ---------------- Flash attention (causal, GQA) ----------------
// Q: [4096][4096] bf16 (row=b*2048+s, col=h*128+d)
// K: [4096][1024] bf16 (col=kvh*128+d)
// Vt:[b][kvh][128][2048] bf16
// O: [4096][4096] bf16
__global__ __launch_bounds__(256) void flash_kernel(
    const u16* __restrict__ Q, const u16* __restrict__ K,
    const u16* __restrict__ Vt, u16* __restrict__ O) {
  __shared__ alignas(16) u16 Ks[64 * 128];
  __shared__ alignas(16) u16 Vs[128 * 64];
  __shared__ alignas(16) u16 Ps[4 * 32 * 72];

  const int tid = threadIdx.x;
  const int w = tid >> 6, lane = tid & 63;
  const int lq = lane & 15, qd = lane >> 4;
  const int bh = blockIdx.y;
  const int b = bh >> 5, h = bh & 31, kvh = h >> 2;
  const int q0 = blockIdx.x * 128;

  // Q fragments, direct from global (A-layout: m=lq, k=qd*8+j)
  short8 qf[2][4];
  {
    const u16* qp = Q + ((size_t)(b * 2048 + q0 + w * 32 + lq) * 4096 + h * 128 + qd * 8);
#pragma unroll
    for (int tm = 0; tm < 2; ++tm)
#pragma unroll
      for (int ks = 0; ks < 4; ++ks)
        qf[tm][ks] = *(const short8*)(qp + (size_t)tm * 16 * 4096 + ks * 32);
  }

  f32x4 o[2][8] = {};
  float mprev[2][4], lsum[2][4];
#pragma unroll
  for (int tm = 0; tm < 2; ++tm)
#pragma unroll
    for (int r = 0; r < 4; ++r) { mprev[tm][r] = -1e30f; lsum[tm][r] = 0.f; }

  const float scale = 0.08838834764831845f;  // 1/sqrt(128)
  const int kv_end = q0 + 128;

  for (int kv0 = 0; kv0 < kv_end; kv0 += 64) {
    // stage K tile: Ks[kv][d], 64 rows x 256B
    {
      const u16* kp = K + ((size_t)(b * 2048 + kv0 + w * 16 + qd) * 1024 + kvh * 128 + lq * 8);
      ushort* dummy;
      (void)dummy;
#pragma unroll
      for (int i = 0; i < 4; ++i)
        gl2lds16(kp + (size_t)(i * 4) * 1024, &Ks[(w * 16 + i * 4) * 128]);
      // stage V tile transposed: Vs[d][kv], 128 rows x 128B
      const u16* vp = Vt + ((size_t)((b * 8 + kvh) * 128 + w * 32 + (lane >> 3)) * 2048 + kv0 + (lane & 7) * 8);
#pragma unroll
      for (int i = 0; i < 4; ++i)
        gl2lds16(vp + (size_t)(i * 8) * 2048, &Vs[(w * 32 + i * 8) * 64]);
    }
    __syncthreads();

    // S = Q K^T  (per wave: 32 q-rows x 64 kv)
    f32x4 s[2][4] = {};
#pragma unroll
    for (int ks = 0; ks < 4; ++ks) {
      short8 kf[4];
#pragma unroll
      for (int tn = 0; tn < 4; ++tn)
        kf[tn] = *(const short8*)&Ks[(tn * 16 + lq) * 128 + ks * 32 + qd * 8];
#pragma unroll
      for (int tm = 0; tm < 2; ++tm)
#pragma unroll
        for (int tn = 0; tn < 4; ++tn)
          s[tm][tn] = mfma_bf16(qf[tm][ks], kf[tn], s[tm][tn]);
    }

    const bool need_mask = (kv0 + 63 > q0);

#pragma unroll
    for (int tm = 0; tm < 2; ++tm) {
      const int row0 = q0 + w * 32 + tm * 16 + qd * 4;
      // scale + causal mask
#pragma unroll
      for (int tn = 0; tn < 4; ++tn) {
        const int col = kv0 + tn * 16 + lq;
#pragma unroll
        for (int r = 0; r < 4; ++r) {
          float v = s[tm][tn][r] * scale;
          if (need_mask && col > row0 + r) v = -1e30f;
          s[tm][tn][r] = v;
        }
      }
      // online softmax
      float mnew[4], alpha[4], rs[4];
#pragma unroll
      for (int r = 0; r < 4; ++r) {
        float t = fmaxf(fmaxf(s[tm][0][r], s[tm][1][r]), fmaxf(s[tm][2][r], s[tm][3][r]));
        t = fmaxf(t, __shfl_xor(t, 1));
        t = fmaxf(t, __shfl_xor(t, 2));
        t = fmaxf(t, __shfl_xor(t, 4));
        t = fmaxf(t, __shfl_xor(t, 8));
        mnew[r] = fmaxf(mprev[tm][r], t);
        alpha[r] = __expf(mprev[tm][r] - mnew[r]);
        mprev[tm][r] = mnew[r];
        rs[r] = 0.f;
      }
#pragma unroll
      for (int tn = 0; tn < 4; ++tn)
#pragma unroll
        for (int r = 0; r < 4; ++r) {
          float p = __expf(s[tm][tn][r] - mnew[r]);
          rs[r] += p;
          Ps[w * (32 * 72) + (tm * 16 + qd * 4 + r) * 72 + tn * 16 + lq] = f2bf(p);
        }
#pragma unroll
      for (int r = 0; r < 4; ++r) {
        float t = rs[r];
        t += __shfl_xor(t, 1);
        t += __shfl_xor(t, 2);
        t += __shfl_xor(t, 4);
        t += __shfl_xor(t, 8);
        lsum[tm][r] = lsum[tm][r] * alpha[r] + t;
      }
#pragma unroll
      for (int n = 0; n < 8; ++n)
#pragma unroll
        for (int r = 0; r < 4; ++r)
          o[tm][n][r] *= alpha[r];
    }

    // O += P @ V   (P from per-wave LDS in A-layout; Vs[d][kv] gives B-frags)
#pragma unroll
    for (int kst = 0; kst < 2; ++kst) {
      short8 af[2];
#pragma unroll
      for (int tm = 0; tm < 2; ++tm)
        af[tm] = *(const short8*)&Ps[w * (32 * 72) + (tm * 16 + lq) * 72 + kst * 32 + qd * 8];
#pragma unroll
      for (int n = 0; n < 8; ++n) {
        short8 bf = *(const short8*)&Vs[(n * 16 + lq) * 64 + kst * 32 + qd * 8];
#pragma unroll
        for (int tm = 0; tm < 2; ++tm)
          o[tm][n] = mfma_bf16(af[tm], bf, o[tm][n]);
      }
    }
    __syncthreads();
  }

  // epilogue: O / l -> bf16
#pragma unroll
  for (int tm = 0; tm < 2; ++tm) {
    const int row = b * 2048 + q0 + w * 32 + tm * 16 + qd * 4;
#pragma unroll
    for (int r = 0; r < 4; ++r) {
      const float inv = 1.f / lsum[tm][r];
      u16* op = O + ((size_t)(row + r) * 4096 + h * 128 + lq);
#pragma unroll
      for (int n = 0; n < 8; ++n)
        op[n * 16] = f2bf(o[tm][n][r] * inv);
    }
  }
}

// ---------------- launcher ----------------
extern "C" void kernel_launch(void* const* d_in, const int* in_sizes, int n_in,
                              void* d_out, int out_size, void* d_ws, size_t ws_size,
                              hipStream_t stream) {
  const float* hidden = (const float*)d_in[0];
  const int* pos = (const int*)d_in[1];
  const float* Wq = (const float*)d_in[2];
  const float* Wk = (const float*)d_in[3];
  const float* Wv = (const float*)d_in[4];
  const float* Wo = (const float*)d_in[5];
  float* out = (float*)d_out;

  char* ws = (char*)d_ws;
  u16* hbf   = (u16*)(ws);                       // 4096x4096 bf16     (32 MiB)
  u16* wqkvt = (u16*)(ws + 33554432ull);         // 6144x4096 bf16 B^T (48 MiB)
  u16* wot   = (u16*)(ws + 83886080ull);         // 4096x4096 bf16 B^T (32 MiB)
  u16* qkvbf = (u16*)(ws + 117440512ull);        // 4096x6144 bf16     (48 MiB)
  u16* qbf   = (u16*)(ws + 167772160ull);        // 4096x4096 bf16
  u16* kbf   = (u16*)(ws + 201326592ull);        // 4096x1024 bf16
  u16* vt    = (u16*)(ws + 209715200ull);        // 2x8x128x2048 bf16
  u16* obf   = (u16*)(ws + 218103808ull);        // 4096x4096 bf16 (ends at 240 MiB)

  // 1. dtype conversions
  f32_to_bf16_kernel<<<16384, 256, 0, stream>>>(hidden, hbf, 16777216);
  transpose_w_kernel<<<dim3(128, 128), dim3(32, 8), 0, stream>>>(Wq, wqkvt, 4096, 4096);
  transpose_w_kernel<<<dim3(32, 128), dim3(32, 8), 0, stream>>>(Wk, wqkvt + (size_t)4096 * 4096, 4096, 1024);
  transpose_w_kernel<<<dim3(32, 128), dim3(32, 8), 0, stream>>>(Wv, wqkvt + (size_t)5120 * 4096, 4096, 1024);
  transpose_w_kernel<<<dim3(128, 128), dim3(32, 8), 0, stream>>>(Wo, wot, 4096, 4096);

  // 2. fused QKV projection: [4096,4096] @ [4096,6144] -> bf16 [4096,6144]
  gemm_bt<true><<<dim3(48, 32), 256, 0, stream>>>(hbf, wqkvt, nullptr, qkvbf, 4096, 6144);

  // 3. RoPE on Q and K
  rope_kernel<<<32768, 256, 0, stream>>>(qkvbf, qbf, pos, 32, 0, 4096, 8388608);
  rope_kernel<<<8192, 256, 0, stream>>>(qkvbf, kbf, pos, 8, 4096, 1024, 2097152);

  // 4. V transpose for PV B-operand layout
  vt_kernel<<<dim3(64, 4, 16), dim3(32, 8), 0, stream>>>(qkvbf, vt);

  // 5. causal flash attention
  flash_kernel<<<dim3(16, 64), 256, 0, stream>>>(qbf, kbf, vt, obf);

  // 6. output projection -> fp32 out
  gemm_bt<false><<<dim3(32, 32), 256, 0, stream>>>(obf, wot, out, nullptr, 4096, 4096);
}

// Round 2
// 1088.058 us; speedup vs baseline: 1.1327x; 1.1327x over previous
//
#include <hip/hip_runtime.h>
#include <cstdint>
#include <cstddef>

typedef unsigned short u16;
typedef unsigned int u32;
typedef short short8 __attribute__((ext_vector_type(8)));
typedef float f32x4 __attribute__((ext_vector_type(4)));

__device__ __forceinline__ u16 f2bf(float f) {
  unsigned u = __float_as_uint(f);
  u += 0x7fffu + ((u >> 16) & 1u);
  return (u16)(u >> 16);
}
__device__ __forceinline__ float bf2f(u16 h) {
  return __uint_as_float(((unsigned)h) << 16);
}
__device__ __forceinline__ u32 pack_bf2(float lo, float hi) {
  return ((u32)f2bf(hi) << 16) | (u32)f2bf(lo);
}

typedef const __attribute__((address_space(1))) unsigned int gu32_t;
typedef __attribute__((address_space(3))) unsigned int su32_t;
__device__ __forceinline__ void gl2lds16(const void* g, void* l) {
  __builtin_amdgcn_global_load_lds((gu32_t*)g, (su32_t*)l, 16, 0, 0);
}

__device__ __forceinline__ f32x4 mfma_bf16(short8 a, short8 b, f32x4 c) {
  return __builtin_amdgcn_mfma_f32_16x16x32_bf16(a, b, c, 0, 0, 0);
}

// ---------------- elementwise fp32 -> bf16 ----------------
__global__ __launch_bounds__(256) void f32_to_bf16_kernel(
    const float* __restrict__ x, u16* __restrict__ y, int n) {
  int i = (blockIdx.x * 256 + threadIdx.x) * 4;
  if (i + 3 < n) {
    float4 v = *(const float4*)(x + i);
    ushort4 o;
    o.x = f2bf(v.x); o.y = f2bf(v.y); o.z = f2bf(v.z); o.w = f2bf(v.w);
    *(ushort4*)(y + i) = o;
  }
}

// ---------------- W [K][N] fp32 -> Wt [N][K] bf16 (tiled transpose) ----------------
__global__ __launch_bounds__(256) void transpose_w_kernel(
    const float* __restrict__ W, u16* __restrict__ Wt, int K, int N) {
  __shared__ float tile[32][33];
  int n0 = blockIdx.x * 32, k0 = blockIdx.y * 32;
  int tx = threadIdx.x, ty = threadIdx.y;
#pragma unroll
  for (int j = 0; j < 4; ++j)
    tile[ty + j * 8][tx] = W[(size_t)(k0 + ty + j * 8) * N + n0 + tx];
  __syncthreads();
#pragma unroll
  for (int j = 0; j < 4; ++j)
    Wt[(size_t)(n0 + ty + j * 8) * K + k0 + tx] = f2bf(tile[tx][ty + j * 8]);
}

// ---------------- GEMM: C[M][ldc] = A[M][K] @ Bt[N][K]^T  (bf16 in, fp32 acc) ----------------
template <bool BF16OUT>
__global__ __launch_bounds__(256) void gemm_bt(
    const u16* __restrict__ A, const u16* __restrict__ Bt,
    float* __restrict__ Cf, u16* __restrict__ Cb, int K, int ldc) {
  __shared__ alignas(16) u16 As[128 * 32];
  __shared__ alignas(16) u16 Bs[128 * 32];
  const int tid = threadIdx.x;
  const int w = tid >> 6, lane = tid & 63;
  const int lq = lane & 15, qd = lane >> 4;
  const int wm = w >> 1, wn = w & 1;
  const int m0 = blockIdx.y * 128, n0 = blockIdx.x * 128;
  const int r4 = lane >> 2, c8 = (lane & 3) * 8;

  f32x4 acc[4][4] = {};

  const u16* ap = A + ((size_t)(m0 + w * 16 + r4) * K + c8);
  const u16* bp = Bt + ((size_t)(n0 + w * 16 + r4) * K + c8);
  u16* asd0 = &As[(w * 16) * 32];
  u16* asd1 = &As[(64 + w * 16) * 32];
  u16* bsd0 = &Bs[(w * 16) * 32];
  u16* bsd1 = &Bs[(64 + w * 16) * 32];

  for (int k0 = 0; k0 < K; k0 += 32) {
    gl2lds16(ap + k0, asd0);
    gl2lds16(ap + (size_t)64 * K + k0, asd1);
    gl2lds16(bp + k0, bsd0);
    gl2lds16(bp + (size_t)64 * K + k0, bsd1);
    __syncthreads();
    short8 af[4], bf[4];
#pragma unroll
    for (int i = 0; i < 4; ++i)
      af[i] = *(const short8*)&As[(wm * 64 + i * 16 + lq) * 32 + qd * 8];
#pragma unroll
    for (int j = 0; j < 4; ++j)
      bf[j] = *(const short8*)&Bs[(wn * 64 + j * 16 + lq) * 32 + qd * 8];
#pragma unroll
    for (int i = 0; i < 4; ++i)
#pragma unroll
      for (int j = 0; j < 4; ++j)
        acc[i][j] = mfma_bf16(af[i], bf[j], acc[i][j]);
    __syncthreads();
  }

#pragma unroll
  for (int i = 0; i < 4; ++i) {
    const int row = m0 + wm * 64 + i * 16 + qd * 4;
#pragma unroll
    for (int j = 0; j < 4; ++j) {
      const int col = n0 + wn * 64 + j * 16 + lq;
#pragma unroll
      for (int r = 0; r < 4; ++r) {
        if (BF16OUT)
          Cb[(size_t)(row + r) * ldc + col] = f2bf(acc[i][j][r]);
        else
          Cf[(size_t)(row + r) * ldc + col] = acc[i][j][r];
      }
    }
  }
}

// ---------------- RoPE: qkv_bf slice -> rotated bf16 dst (optionally pre-scaled) ----------------
__global__ __launch_bounds__(256) void rope_kernel(
    const u16* __restrict__ src, u16* __restrict__ dst,
    const int* __restrict__ pos_ids, int nh, int src_col0, int dst_ld, int total,
    float scale) {
  int idx = blockIdx.x * 256 + threadIdx.x;
  if (idx >= total) return;
  int i = idx & 63;
  int t = idx >> 6;  // m*nh + hh
  int hh = t % nh;
  int m = t / nh;
  float pos = (float)pos_ids[m];
  float inv = exp2f(-(float)i * 0.20762050593046016f);
  float f = pos * inv;
  float c = cosf(f) * scale, s = sinf(f) * scale;
  const u16* sp = src + (size_t)m * 6144 + src_col0 + hh * 128;
  float x0 = bf2f(sp[i]);
  float x1 = bf2f(sp[i + 64]);
  u16* dp = dst + (size_t)m * dst_ld + hh * 128;
  dp[i] = f2bf(x0 * c - x1 * s);
  dp[i + 64] = f2bf(x1 * c + x0 * s);
}

// ---------------- V transpose: qkv_bf[.,5120+kvh*128+d] -> Vt[b][kvh][d][s] ----------------
__global__ __launch_bounds__(256) void vt_kernel(
    const u16* __restrict__ src, u16* __restrict__ vt) {
  __shared__ u16 tile[32][33];
  int s0 = blockIdx.x * 32;
  int d0 = blockIdx.y * 32;
  int bz = blockIdx.z;
  int b = bz >> 3, kvh = bz & 7;
  int tx = threadIdx.x, ty = threadIdx.y;
#pragma unroll
  for (int j = 0; j < 4; ++j)
    tile[ty + j * 8][tx] =
        src[(size_t)(b * 2048 + s0 + ty + j * 8) * 6144 + 5120 + kvh * 128 + d0 + tx];
  __syncthreads();
#pragma unroll
  for (int j = 0; j < 4; ++j)
    vt[((size_t)(b * 8 + kvh) * 128 + d0 + ty + j * 8) * 2048 + s0 + tx] =
        tile[tx][ty + j * 8];
}

// ---------------- Flash attention (causal, GQA), transposed S/O ----------------
// Q: [4096][4096] bf16 (pre-scaled by 1/sqrt(128)); K: [4096][1024] bf16
// Vt:[b][kvh][128][2048] bf16;  O: [4096][4096] bf16
// Per block: 128 q rows (4 waves x 32 q), kv tiles of 64.
// S^T = K·Q^T (C-layout: col=q, row=kv)  ->  O^T = V^T·P^T (C-layout: col=q, row=d)
__global__ __launch_bounds__(256, 3) void flash_kernel(
    const u16* __restrict__ Q, const u16* __restrict__ K,
    const u16* __restrict__ Vt, u16* __restrict__ O) {
  __shared__ alignas(16) u16 Ks[64 * 128];   // [kv][d]
  __shared__ alignas(16) u16 Vs[128 * 64];   // [d][kv]
  __shared__ alignas(16) u16 Ps[4][32 * 72]; // per-wave [q][kv], ld=72

  const int tid = threadIdx.x;
  const int w = tid >> 6, lane = tid & 63;
  const int lq = lane & 15, qd = lane >> 4;
  const int bh = blockIdx.y;
  const int b = bh >> 5, h = bh & 31, kvh = h >> 2;
  // reversed q-tile order: biggest causal workload dispatched first
  const int q0 = (gridDim.x - 1 - blockIdx.x) * 128;

  // Q fragments (B-operand layout: n=lq -> q, k=qd*8+j -> d). Same bytes as A-layout.
  short8 qf[2][4];
  {
    const u16* qp = Q + ((size_t)(b * 2048 + q0 + w * 32 + lq) * 4096 + h * 128 + qd * 8);
#pragma unroll
    for (int n = 0; n < 2; ++n)
#pragma unroll
      for (int ks = 0; ks < 4; ++ks)
        qf[n][ks] = *(const short8*)(qp + (size_t)n * 16 * 4096 + ks * 32);
  }

  f32x4 ot[2][8] = {};          // O^T tiles: [q-tile][d-tile], col=q(lq), row=d
  float mprev[2], lsum[2];
#pragma unroll
  for (int n = 0; n < 2; ++n) { mprev[n] = -1e30f; lsum[n] = 0.f; }

  const int kv_end = q0 + 128;

  for (int kv0 = 0; kv0 < kv_end; kv0 += 64) {
    // stage K tile: Ks[kv][d]
    {
      const u16* kp = K + ((size_t)(b * 2048 + kv0 + w * 16 + qd) * 1024 + kvh * 128 + lq * 8);
#pragma unroll
      for (int i = 0; i < 4; ++i)
        gl2lds16(kp + (size_t)(i * 4) * 1024, &Ks[(w * 16 + i * 4) * 128]);
      // stage V tile: Vs[d][kv]
      const u16* vp = Vt + ((size_t)((b * 8 + kvh) * 128 + w * 32 + (lane >> 3)) * 2048 + kv0 + (lane & 7) * 8);
#pragma unroll
      for (int i = 0; i < 4; ++i)
        gl2lds16(vp + (size_t)(i * 8) * 2048, &Vs[(w * 32 + i * 8) * 64]);
    }
    __syncthreads();

    // S^T = K Q^T : st[m' kv-tile][n' q-tile], lane holds col q=lq, rows kv=m'*16+qd*4+r
    f32x4 st[4][2] = {};
#pragma unroll
    for (int ks = 0; ks < 4; ++ks) {
      short8 kf[4];
#pragma unroll
      for (int m = 0; m < 4; ++m)
        kf[m] = *(const short8*)&Ks[(m * 16 + lq) * 128 + ks * 32 + qd * 8];
#pragma unroll
      for (int m = 0; m < 4; ++m)
#pragma unroll
        for (int n = 0; n < 2; ++n)
          st[m][n] = mfma_bf16(kf[m], qf[n][ks], st[m][n]);
    }

    // causal mask (diagonal tiles only)
    if (kv0 + 63 > q0) {
#pragma unroll
      for (int n = 0; n < 2; ++n) {
        const int qrow = q0 + w * 32 + n * 16 + lq;
#pragma unroll
        for (int m = 0; m < 4; ++m) {
          const int kvb = kv0 + m * 16 + qd * 4;
#pragma unroll
          for (int r = 0; r < 4; ++r)
            if (kvb + r > qrow) st[m][n][r] = -1e30f;
        }
      }
    }

    // online softmax per q-column (per lane, per n')
#pragma unroll
    for (int n = 0; n < 2; ++n) {
      float t = st[0][n][0];
#pragma unroll
      for (int m = 0; m < 4; ++m)
#pragma unroll
        for (int r = 0; r < 4; ++r) t = fmaxf(t, st[m][n][r]);
      t = fmaxf(t, __shfl_xor(t, 16));
      t = fmaxf(t, __shfl_xor(t, 32));
      const float mnew = fmaxf(mprev[n], t);
      const float alpha = __expf(mprev[n] - mnew);
      mprev[n] = mnew;

      float rs = 0.f;
      u32 pk[4][2];
#pragma unroll
      for (int m = 0; m < 4; ++m) {
        float p0 = __expf(st[m][n][0] - mnew);
        float p1 = __expf(st[m][n][1] - mnew);
        float p2 = __expf(st[m][n][2] - mnew);
        float p3 = __expf(st[m][n][3] - mnew);
        rs += (p0 + p1) + (p2 + p3);
        pk[m][0] = pack_bf2(p0, p1);
        pk[m][1] = pack_bf2(p2, p3);
      }
      rs += __shfl_xor(rs, 16);
      rs += __shfl_xor(rs, 32);
      lsum[n] = lsum[n] * alpha + rs;

      // write P[q][kv] packed: 4 contiguous kv per b64
      u16* pw = &Ps[w][(n * 16 + lq) * 72 + qd * 4];
#pragma unroll
      for (int m = 0; m < 4; ++m)
        *(uint2*)(pw + m * 16) = make_uint2(pk[m][0], pk[m][1]);

      // rescale O^T
#pragma unroll
      for (int mt = 0; mt < 8; ++mt)
#pragma unroll
        for (int r = 0; r < 4; ++r) ot[n][mt][r] *= alpha;
    }

    // O^T += V^T P^T : A = Vs[d][kv] frags, B = Ps[q][kv] frags
#pragma unroll
    for (int kst = 0; kst < 2; ++kst) {
      short8 bp[2];
#pragma unroll
      for (int n = 0; n < 2; ++n)
        bp[n] = *(const short8*)&Ps[w][(n * 16 + lq) * 72 + kst * 32 + qd * 8];
#pragma unroll
      for (int mt = 0; mt < 8; ++mt) {
        short8 av = *(const short8*)&Vs[(mt * 16 + lq) * 64 + kst * 32 + qd * 8];
#pragma unroll
        for (int n = 0; n < 2; ++n)
          ot[n][mt] = mfma_bf16(av, bp[n], ot[n][mt]);
      }
    }
    __syncthreads();
  }

  // epilogue: lane holds col q=lq, rows d = mt*16+qd*4+r -> 4 contiguous d per store
#pragma unroll
  for (int n = 0; n < 2; ++n) {
    const float inv = 1.f / lsum[n];
    const size_t row = (size_t)(b * 2048 + q0 + w * 32 + n * 16 + lq);
    u16* op = O + row * 4096 + h * 128 + qd * 4;
#pragma unroll
    for (int mt = 0; mt < 8; ++mt) {
      u32 a = pack_bf2(ot[n][mt][0] * inv, ot[n][mt][1] * inv);
      u32 c = pack_bf2(ot[n][mt][2] * inv, ot[n][mt][3] * inv);
      *(uint2*)(op + mt * 16) = make_uint2(a, c);
    }
  }
}

// ---------------- launcher ----------------
extern "C" void kernel_launch(void* const* d_in, const int* in_sizes, int n_in,
                              void* d_out, int out_size, void* d_ws, size_t ws_size,
                              hipStream_t stream) {
  const float* hidden = (const float*)d_in[0];
  const int* pos = (const int*)d_in[1];
  const float* Wq = (const float*)d_in[2];
  const float* Wk = (const float*)d_in[3];
  const float* Wv = (const float*)d_in[4];
  const float* Wo = (const float*)d_in[5];
  float* out = (float*)d_out;

  char* ws = (char*)d_ws;
  u16* hbf   = (u16*)(ws);                       // 4096x4096 bf16     (32 MiB)
  u16* wqkvt = (u16*)(ws + 33554432ull);         // 6144x4096 bf16 B^T (48 MiB)
  u16* wot   = (u16*)(ws + 83886080ull);         // 4096x4096 bf16 B^T (32 MiB)
  u16* qkvbf = (u16*)(ws + 117440512ull);        // 4096x6144 bf16     (48 MiB)
  u16* qbf   = (u16*)(ws + 167772160ull);        // 4096x4096 bf16
  u16* kbf   = (u16*)(ws + 201326592ull);        // 4096x1024 bf16
  u16* vt    = (u16*)(ws + 209715200ull);        // 2x8x128x2048 bf16
  u16* obf   = (u16*)(ws + 218103808ull);        // 4096x4096 bf16 (ends at 240 MiB)

  // 1. dtype conversions
  f32_to_bf16_kernel<<<16384, 256, 0, stream>>>(hidden, hbf, 16777216);
  transpose_w_kernel<<<dim3(128, 128), dim3(32, 8), 0, stream>>>(Wq, wqkvt, 4096, 4096);
  transpose_w_kernel<<<dim3(32, 128), dim3(32, 8), 0, stream>>>(Wk, wqkvt + (size_t)4096 * 4096, 4096, 1024);
  transpose_w_kernel<<<dim3(32, 128), dim3(32, 8), 0, stream>>>(Wv, wqkvt + (size_t)5120 * 4096, 4096, 1024);
  transpose_w_kernel<<<dim3(128, 128), dim3(32, 8), 0, stream>>>(Wo, wot, 4096, 4096);

  // 2. fused QKV projection
  gemm_bt<true><<<dim3(48, 32), 256, 0, stream>>>(hbf, wqkvt, nullptr, qkvbf, 4096, 6144);

  // 3. RoPE on Q (pre-scaled by 1/sqrt(128)) and K
  rope_kernel<<<32768, 256, 0, stream>>>(qkvbf, qbf, pos, 32, 0, 4096, 8388608, 0.08838834764831845f);
  rope_kernel<<<8192, 256, 0, stream>>>(qkvbf, kbf, pos, 8, 4096, 1024, 2097152, 1.0f);

  // 4. V transpose
  vt_kernel<<<dim3(64, 4, 16), dim3(32, 8), 0, stream>>>(qkvbf, vt);

  // 5. causal flash attention (transposed S/O)
  flash_kernel<<<dim3(16, 64), 256, 0, stream>>>(qbf, kbf, vt, obf);

  // 6. output projection -> fp32 out
  gemm_bt<false><<<dim3(32, 32), 256, 0, stream>>>(obf, wot, out, nullptr, 4096, 4096);
}

// Round 3
// 1030.745 us; speedup vs baseline: 1.1957x; 1.0556x over previous
//
#include <hip/hip_runtime.h>
#include <cstdint>
#include <cstddef>

typedef unsigned short u16;
typedef unsigned int u32;
typedef short short8 __attribute__((ext_vector_type(8)));
typedef float f32x4 __attribute__((ext_vector_type(4)));

__device__ __forceinline__ u16 f2bf(float f) {
  unsigned u = __float_as_uint(f);
  u += 0x7fffu + ((u >> 16) & 1u);
  return (u16)(u >> 16);
}
__device__ __forceinline__ float bf2f(u16 h) {
  return __uint_as_float(((unsigned)h) << 16);
}
__device__ __forceinline__ u32 pack_bf2(float lo, float hi) {
  return ((u32)f2bf(hi) << 16) | (u32)f2bf(lo);
}

typedef const __attribute__((address_space(1))) unsigned int gu32_t;
typedef __attribute__((address_space(3))) unsigned int su32_t;
__device__ __forceinline__ void gl2lds16(const void* g, void* l) {
  __builtin_amdgcn_global_load_lds((gu32_t*)g, (su32_t*)l, 16, 0, 0);
}

__device__ __forceinline__ f32x4 mfma_bf16(short8 a, short8 b, f32x4 c) {
  return __builtin_amdgcn_mfma_f32_16x16x32_bf16(a, b, c, 0, 0, 0);
}

// ---------------- elementwise fp32 -> bf16 ----------------
__global__ __launch_bounds__(256) void f32_to_bf16_kernel(
    const float* __restrict__ x, u16* __restrict__ y, int n) {
  int i = (blockIdx.x * 256 + threadIdx.x) * 4;
  if (i + 3 < n) {
    float4 v = *(const float4*)(x + i);
    ushort4 o;
    o.x = f2bf(v.x); o.y = f2bf(v.y); o.z = f2bf(v.z); o.w = f2bf(v.w);
    *(ushort4*)(y + i) = o;
  }
}

// ---------------- W [K][N] fp32 -> Wt [N][K] bf16 (tiled transpose) ----------------
__global__ __launch_bounds__(256) void transpose_w_kernel(
    const float* __restrict__ W, u16* __restrict__ Wt, int K, int N) {
  __shared__ float tile[32][33];
  int n0 = blockIdx.x * 32, k0 = blockIdx.y * 32;
  int tx = threadIdx.x, ty = threadIdx.y;
#pragma unroll
  for (int j = 0; j < 4; ++j)
    tile[ty + j * 8][tx] = W[(size_t)(k0 + ty + j * 8) * N + n0 + tx];
  __syncthreads();
#pragma unroll
  for (int j = 0; j < 4; ++j)
    Wt[(size_t)(n0 + ty + j * 8) * K + k0 + tx] = f2bf(tile[tx][ty + j * 8]);
}

// ---------------- GEMM: C[M][ldc] = A[M][K] @ Bt[N][K]^T  (bf16 in, fp32 acc) ----------------
template <bool BF16OUT>
__global__ __launch_bounds__(256) void gemm_bt(
    const u16* __restrict__ A, const u16* __restrict__ Bt,
    float* __restrict__ Cf, u16* __restrict__ Cb, int K, int ldc) {
  __shared__ alignas(16) u16 As[128 * 32];
  __shared__ alignas(16) u16 Bs[128 * 32];
  const int tid = threadIdx.x;
  const int w = tid >> 6, lane = tid & 63;
  const int lq = lane & 15, qd = lane >> 4;
  const int wm = w >> 1, wn = w & 1;
  const int m0 = blockIdx.y * 128, n0 = blockIdx.x * 128;
  const int r4 = lane >> 2, c8 = (lane & 3) * 8;

  f32x4 acc[4][4] = {};

  const u16* ap = A + ((size_t)(m0 + w * 16 + r4) * K + c8);
  const u16* bp = Bt + ((size_t)(n0 + w * 16 + r4) * K + c8);
  u16* asd0 = &As[(w * 16) * 32];
  u16* asd1 = &As[(64 + w * 16) * 32];
  u16* bsd0 = &Bs[(w * 16) * 32];
  u16* bsd1 = &Bs[(64 + w * 16) * 32];

  for (int k0 = 0; k0 < K; k0 += 32) {
    gl2lds16(ap + k0, asd0);
    gl2lds16(ap + (size_t)64 * K + k0, asd1);
    gl2lds16(bp + k0, bsd0);
    gl2lds16(bp + (size_t)64 * K + k0, bsd1);
    __syncthreads();
    short8 af[4], bf[4];
#pragma unroll
    for (int i = 0; i < 4; ++i)
      af[i] = *(const short8*)&As[(wm * 64 + i * 16 + lq) * 32 + qd * 8];
#pragma unroll
    for (int j = 0; j < 4; ++j)
      bf[j] = *(const short8*)&Bs[(wn * 64 + j * 16 + lq) * 32 + qd * 8];
#pragma unroll
    for (int i = 0; i < 4; ++i)
#pragma unroll
      for (int j = 0; j < 4; ++j)
        acc[i][j] = mfma_bf16(af[i], bf[j], acc[i][j]);
    __syncthreads();
  }

#pragma unroll
  for (int i = 0; i < 4; ++i) {
    const int row = m0 + wm * 64 + i * 16 + qd * 4;
#pragma unroll
    for (int j = 0; j < 4; ++j) {
      const int col = n0 + wn * 64 + j * 16 + lq;
#pragma unroll
      for (int r = 0; r < 4; ++r) {
        if (BF16OUT)
          Cb[(size_t)(row + r) * ldc + col] = f2bf(acc[i][j][r]);
        else
          Cf[(size_t)(row + r) * ldc + col] = acc[i][j][r];
      }
    }
  }
}

// ---------------- RoPE ----------------
__global__ __launch_bounds__(256) void rope_kernel(
    const u16* __restrict__ src, u16* __restrict__ dst,
    const int* __restrict__ pos_ids, int nh, int src_col0, int dst_ld, int total,
    float scale) {
  int idx = blockIdx.x * 256 + threadIdx.x;
  if (idx >= total) return;
  int i = idx & 63;
  int t = idx >> 6;
  int hh = t % nh;
  int m = t / nh;
  float pos = (float)pos_ids[m];
  float inv = exp2f(-(float)i * 0.20762050593046016f);
  float f = pos * inv;
  float c = cosf(f) * scale, s = sinf(f) * scale;
  const u16* sp = src + (size_t)m * 6144 + src_col0 + hh * 128;
  float x0 = bf2f(sp[i]);
  float x1 = bf2f(sp[i + 64]);
  u16* dp = dst + (size_t)m * dst_ld + hh * 128;
  dp[i] = f2bf(x0 * c - x1 * s);
  dp[i + 64] = f2bf(x1 * c + x0 * s);
}

// ---------------- V transpose ----------------
__global__ __launch_bounds__(256) void vt_kernel(
    const u16* __restrict__ src, u16* __restrict__ vt) {
  __shared__ u16 tile[32][33];
  int s0 = blockIdx.x * 32;
  int d0 = blockIdx.y * 32;
  int bz = blockIdx.z;
  int b = bz >> 3, kvh = bz & 7;
  int tx = threadIdx.x, ty = threadIdx.y;
#pragma unroll
  for (int j = 0; j < 4; ++j)
    tile[ty + j * 8][tx] =
        src[(size_t)(b * 2048 + s0 + ty + j * 8) * 6144 + 5120 + kvh * 128 + d0 + tx];
  __syncthreads();
#pragma unroll
  for (int j = 0; j < 4; ++j)
    vt[((size_t)(b * 8 + kvh) * 128 + d0 + ty + j * 8) * 2048 + s0 + tx] =
        tile[tx][ty + j * 8];
}

// ---------------- Flash attention (causal, GQA), transposed S/O, XOR-swizzled LDS ----
// Swizzle: row r's logical 16B chunk c lives at physical chunk (c ^ (r&7)).
// Staging lane (placed at physical chunk by global_load_lds) fetches the
// matching logical chunk from global; readers XOR their chunk index with lq&7.
#define PS_LD 76
__global__ __launch_bounds__(256, 3) void flash_kernel(
    const u16* __restrict__ Q, const u16* __restrict__ K,
    const u16* __restrict__ Vt, u16* __restrict__ O) {
  __shared__ alignas(16) u16 Ks[64 * 128];     // [kv][d] swizzled
  __shared__ alignas(16) u16 Vs[128 * 64];     // [d][kv] swizzled
  __shared__ alignas(16) u16 Ps[4][32 * PS_LD];

  const int tid = threadIdx.x;
  const int w = tid >> 6, lane = tid & 63;
  const int lq = lane & 15, qd = lane >> 4;
  const int lq7 = lq & 7;
  const int bh = blockIdx.y;
  const int b = bh >> 5, h = bh & 31, kvh = h >> 2;
  const int q0 = (gridDim.x - 1 - blockIdx.x) * 128;

  // Q fragments (B-operand: n=lq -> q, k=qd*8+j -> d)
  short8 qf[2][4];
  {
    const u16* qp = Q + ((size_t)(b * 2048 + q0 + w * 32 + lq) * 4096 + h * 128 + qd * 8);
#pragma unroll
    for (int n = 0; n < 2; ++n)
#pragma unroll
      for (int ks = 0; ks < 4; ++ks)
        qf[n][ks] = *(const short8*)(qp + (size_t)n * 16 * 4096 + ks * 32);
  }

  f32x4 ot[2][8] = {};
  float mprev[2], lsum[2];
#pragma unroll
  for (int n = 0; n < 2; ++n) { mprev[n] = -1e30f; lsum[n] = 0.f; }

  // swizzled staging source-column offsets (per lane, loop-invariant)
  const int rk = lane >> 4;      // K: row-in-group 0..3
  const int pk = lane & 15;      //    physical chunk 0..15
  const int ckA = (pk ^ rk) * 8;          // i even: r&7 = rk
  const int ckB = (pk ^ (4 + rk)) * 8;    // i odd:  r&7 = 4+rk
  const int rv = lane >> 3;      // V: row-in-group 0..7
  const int cv = ((lane & 7) ^ rv) * 8;

  const int kv_end = q0 + 128;

  for (int kv0 = 0; kv0 < kv_end; kv0 += 64) {
    {
      const u16* kbase = K + ((size_t)(b * 2048 + kv0 + w * 16 + rk) * 1024) + kvh * 128;
#pragma unroll
      for (int i = 0; i < 4; ++i)
        gl2lds16(kbase + (size_t)(i * 4) * 1024 + ((i & 1) ? ckB : ckA),
                 &Ks[(w * 16 + i * 4) * 128]);
      const u16* vbase = Vt + ((size_t)((b * 8 + kvh) * 128 + w * 32 + rv) * 2048) + kv0 + cv;
#pragma unroll
      for (int i = 0; i < 4; ++i)
        gl2lds16(vbase + (size_t)(i * 8) * 2048, &Vs[(w * 32 + i * 8) * 64]);
    }
    __syncthreads();

    // S^T = K Q^T : lane holds col q=lq, rows kv = m*16+qd*4+r
    f32x4 st[4][2] = {};
#pragma unroll
    for (int ks = 0; ks < 4; ++ks) {
      short8 kf[4];
#pragma unroll
      for (int m = 0; m < 4; ++m)
        kf[m] = *(const short8*)&Ks[(m * 16 + lq) * 128 + ((ks * 4 + qd) ^ lq7) * 8];
#pragma unroll
      for (int m = 0; m < 4; ++m)
#pragma unroll
        for (int n = 0; n < 2; ++n)
          st[m][n] = mfma_bf16(kf[m], qf[n][ks], st[m][n]);
    }

    // causal mask (diagonal tiles only)
    if (kv0 + 63 > q0) {
#pragma unroll
      for (int n = 0; n < 2; ++n) {
        const int qrow = q0 + w * 32 + n * 16 + lq;
#pragma unroll
        for (int m = 0; m < 4; ++m) {
          const int kvb = kv0 + m * 16 + qd * 4;
#pragma unroll
          for (int r = 0; r < 4; ++r)
            if (kvb + r > qrow) st[m][n][r] = -1e30f;
        }
      }
    }

    // online softmax per q-column
#pragma unroll
    for (int n = 0; n < 2; ++n) {
      float t = st[0][n][0];
#pragma unroll
      for (int m = 0; m < 4; ++m)
#pragma unroll
        for (int r = 0; r < 4; ++r) t = fmaxf(t, st[m][n][r]);
      t = fmaxf(t, __shfl_xor(t, 16));
      t = fmaxf(t, __shfl_xor(t, 32));
      const float mnew = fmaxf(mprev[n], t);
      const float alpha = __expf(mprev[n] - mnew);
      mprev[n] = mnew;

      float rs = 0.f;
      u32 pk2[4][2];
#pragma unroll
      for (int m = 0; m < 4; ++m) {
        float p0 = __expf(st[m][n][0] - mnew);
        float p1 = __expf(st[m][n][1] - mnew);
        float p2 = __expf(st[m][n][2] - mnew);
        float p3 = __expf(st[m][n][3] - mnew);
        rs += (p0 + p1) + (p2 + p3);
        pk2[m][0] = pack_bf2(p0, p1);
        pk2[m][1] = pack_bf2(p2, p3);
      }
      rs += __shfl_xor(rs, 16);
      rs += __shfl_xor(rs, 32);
      lsum[n] = lsum[n] * alpha + rs;

      u16* pw = &Ps[w][(n * 16 + lq) * PS_LD + qd * 4];
#pragma unroll
      for (int m = 0; m < 4; ++m)
        *(uint2*)(pw + m * 16) = make_uint2(pk2[m][0], pk2[m][1]);

#pragma unroll
      for (int mt = 0; mt < 8; ++mt)
#pragma unroll
        for (int r = 0; r < 4; ++r) ot[n][mt][r] *= alpha;
    }

    // O^T += V^T P^T
#pragma unroll
    for (int kst = 0; kst < 2; ++kst) {
      short8 bp[2];
#pragma unroll
      for (int n = 0; n < 2; ++n)
        bp[n] = *(const short8*)&Ps[w][(n * 16 + lq) * PS_LD + kst * 32 + qd * 8];
#pragma unroll
      for (int mt = 0; mt < 8; ++mt) {
        short8 av = *(const short8*)&Vs[(mt * 16 + lq) * 64 + ((kst * 4 + qd) ^ lq7) * 8];
#pragma unroll
        for (int n = 0; n < 2; ++n)
          ot[n][mt] = mfma_bf16(av, bp[n], ot[n][mt]);
      }
    }
    __syncthreads();
  }

  // epilogue
#pragma unroll
  for (int n = 0; n < 2; ++n) {
    const float inv = 1.f / lsum[n];
    const size_t row = (size_t)(b * 2048 + q0 + w * 32 + n * 16 + lq);
    u16* op = O + row * 4096 + h * 128 + qd * 4;
#pragma unroll
    for (int mt = 0; mt < 8; ++mt) {
      u32 a = pack_bf2(ot[n][mt][0] * inv, ot[n][mt][1] * inv);
      u32 c = pack_bf2(ot[n][mt][2] * inv, ot[n][mt][3] * inv);
      *(uint2*)(op + mt * 16) = make_uint2(a, c);
    }
  }
}

// ---------------- launcher ----------------
extern "C" void kernel_launch(void* const* d_in, const int* in_sizes, int n_in,
                              void* d_out, int out_size, void* d_ws, size_t ws_size,
                              hipStream_t stream) {
  const float* hidden = (const float*)d_in[0];
  const int* pos = (const int*)d_in[1];
  const float* Wq = (const float*)d_in[2];
  const float* Wk = (const float*)d_in[3];
  const float* Wv = (const float*)d_in[4];
  const float* Wo = (const float*)d_in[5];
  float* out = (float*)d_out;

  char* ws = (char*)d_ws;
  u16* hbf   = (u16*)(ws);                       // 4096x4096 bf16     (32 MiB)
  u16* wqkvt = (u16*)(ws + 33554432ull);         // 6144x4096 bf16 B^T (48 MiB)
  u16* wot   = (u16*)(ws + 83886080ull);         // 4096x4096 bf16 B^T (32 MiB)
  u16* qkvbf = (u16*)(ws + 117440512ull);        // 4096x6144 bf16     (48 MiB)
  u16* qbf   = (u16*)(ws + 167772160ull);        // 4096x4096 bf16
  u16* kbf   = (u16*)(ws + 201326592ull);        // 4096x1024 bf16
  u16* vt    = (u16*)(ws + 209715200ull);        // 2x8x128x2048 bf16
  u16* obf   = (u16*)(ws + 218103808ull);        // 4096x4096 bf16 (ends at 240 MiB)

  f32_to_bf16_kernel<<<16384, 256, 0, stream>>>(hidden, hbf, 16777216);
  transpose_w_kernel<<<dim3(128, 128), dim3(32, 8), 0, stream>>>(Wq, wqkvt, 4096, 4096);
  transpose_w_kernel<<<dim3(32, 128), dim3(32, 8), 0, stream>>>(Wk, wqkvt + (size_t)4096 * 4096, 4096, 1024);
  transpose_w_kernel<<<dim3(32, 128), dim3(32, 8), 0, stream>>>(Wv, wqkvt + (size_t)5120 * 4096, 4096, 1024);
  transpose_w_kernel<<<dim3(128, 128), dim3(32, 8), 0, stream>>>(Wo, wot, 4096, 4096);

  gemm_bt<true><<<dim3(48, 32), 256, 0, stream>>>(hbf, wqkvt, nullptr, qkvbf, 4096, 6144);

  rope_kernel<<<32768, 256, 0, stream>>>(qkvbf, qbf, pos, 32, 0, 4096, 8388608, 0.08838834764831845f);
  rope_kernel<<<8192, 256, 0, stream>>>(qkvbf, kbf, pos, 8, 4096, 1024, 2097152, 1.0f);

  vt_kernel<<<dim3(64, 4, 16), dim3(32, 8), 0, stream>>>(qkvbf, vt);

  flash_kernel<<<dim3(16, 64), 256, 0, stream>>>(qbf, kbf, vt, obf);

  gemm_bt<false><<<dim3(32, 32), 256, 0, stream>>>(obf, wot, out, nullptr, 4096, 4096);
}

// Round 4
// 1011.528 us; speedup vs baseline: 1.2184x; 1.0190x over previous
//
#include <hip/hip_runtime.h>
#include <cstdint>
#include <cstddef>

typedef unsigned short u16;
typedef unsigned int u32;
typedef short short8 __attribute__((ext_vector_type(8)));
typedef float f32x4 __attribute__((ext_vector_type(4)));

__device__ __forceinline__ u16 f2bf(float f) {
  unsigned u = __float_as_uint(f);
  u += 0x7fffu + ((u >> 16) & 1u);
  return (u16)(u >> 16);
}
__device__ __forceinline__ float bf2f(u16 h) {
  return __uint_as_float(((unsigned)h) << 16);
}
__device__ __forceinline__ u32 pack_bf2(float lo, float hi) {
  return ((u32)f2bf(hi) << 16) | (u32)f2bf(lo);
}

typedef const __attribute__((address_space(1))) unsigned int gu32_t;
typedef __attribute__((address_space(3))) unsigned int su32_t;
__device__ __forceinline__ void gl2lds16(const void* g, void* l) {
  __builtin_amdgcn_global_load_lds((gu32_t*)g, (su32_t*)l, 16, 0, 0);
}

__device__ __forceinline__ f32x4 mfma_bf16(short8 a, short8 b, f32x4 c) {
  return __builtin_amdgcn_mfma_f32_16x16x32_bf16(a, b, c, 0, 0, 0);
}

// ---------------- elementwise fp32 -> bf16 ----------------
__global__ __launch_bounds__(256) void f32_to_bf16_kernel(
    const float* __restrict__ x, u16* __restrict__ y, int n) {
  int i = (blockIdx.x * 256 + threadIdx.x) * 4;
  if (i + 3 < n) {
    float4 v = *(const float4*)(x + i);
    ushort4 o;
    o.x = f2bf(v.x); o.y = f2bf(v.y); o.z = f2bf(v.z); o.w = f2bf(v.w);
    *(ushort4*)(y + i) = o;
  }
}

// ---------------- W [K][N] fp32 -> Wt [N][K] bf16 (tiled transpose) ----------------
__global__ __launch_bounds__(256) void transpose_w_kernel(
    const float* __restrict__ W, u16* __restrict__ Wt, int K, int N) {
  __shared__ float tile[32][33];
  int n0 = blockIdx.x * 32, k0 = blockIdx.y * 32;
  int tx = threadIdx.x, ty = threadIdx.y;
#pragma unroll
  for (int j = 0; j < 4; ++j)
    tile[ty + j * 8][tx] = W[(size_t)(k0 + ty + j * 8) * N + n0 + tx];
  __syncthreads();
#pragma unroll
  for (int j = 0; j < 4; ++j)
    Wt[(size_t)(n0 + ty + j * 8) * K + k0 + tx] = f2bf(tile[tx][ty + j * 8]);
}

// ---------------- GEMM: C[M][ldc] = A[M][K] @ Bt[N][K]^T  (bf16 in, fp32 acc) --------
// LDS XOR swizzle: 64B rows (4x16B chunks); logical chunk c of row r stored at
// physical chunk c ^ ((r>>1)&3) -> b128 reads spread over 8 bank-quads (2-way, free).
template <bool BF16OUT>
__global__ __launch_bounds__(256) void gemm_bt(
    const u16* __restrict__ A, const u16* __restrict__ Bt,
    float* __restrict__ Cf, u16* __restrict__ Cb, int K, int ldc) {
  __shared__ alignas(16) u16 As[128 * 32];
  __shared__ alignas(16) u16 Bs[128 * 32];
  const int tid = threadIdx.x;
  const int w = tid >> 6, lane = tid & 63;
  const int lq = lane & 15, qd = lane >> 4;
  const int wm = w >> 1, wn = w & 1;
  const int m0 = blockIdx.y * 128, n0 = blockIdx.x * 128;
  const int r4 = lane >> 2;
  const int csw = (((lane & 3) ^ ((lane >> 3) & 3)) * 8);  // swizzled source chunk
  const int sa = (lq >> 1) & 3;                            // reader swizzle key

  f32x4 acc[4][4] = {};

  const u16* ap = A + ((size_t)(m0 + w * 16 + r4) * K + csw);
  const u16* bp = Bt + ((size_t)(n0 + w * 16 + r4) * K + csw);
  u16* asd0 = &As[(w * 16) * 32];
  u16* asd1 = &As[(64 + w * 16) * 32];
  u16* bsd0 = &Bs[(w * 16) * 32];
  u16* bsd1 = &Bs[(64 + w * 16) * 32];

  for (int k0 = 0; k0 < K; k0 += 32) {
    gl2lds16(ap + k0, asd0);
    gl2lds16(ap + (size_t)64 * K + k0, asd1);
    gl2lds16(bp + k0, bsd0);
    gl2lds16(bp + (size_t)64 * K + k0, bsd1);
    __syncthreads();
    short8 af[4], bf[4];
#pragma unroll
    for (int i = 0; i < 4; ++i)
      af[i] = *(const short8*)&As[(wm * 64 + i * 16 + lq) * 32 + (qd ^ sa) * 8];
#pragma unroll
    for (int j = 0; j < 4; ++j)
      bf[j] = *(const short8*)&Bs[(wn * 64 + j * 16 + lq) * 32 + (qd ^ sa) * 8];
#pragma unroll
    for (int i = 0; i < 4; ++i)
#pragma unroll
      for (int j = 0; j < 4; ++j)
        acc[i][j] = mfma_bf16(af[i], bf[j], acc[i][j]);
    __syncthreads();
  }

#pragma unroll
  for (int i = 0; i < 4; ++i) {
    const int row = m0 + wm * 64 + i * 16 + qd * 4;
#pragma unroll
    for (int j = 0; j < 4; ++j) {
      const int col = n0 + wn * 64 + j * 16 + lq;
#pragma unroll
      for (int r = 0; r < 4; ++r) {
        if (BF16OUT)
          Cb[(size_t)(row + r) * ldc + col] = f2bf(acc[i][j][r]);
        else
          Cf[(size_t)(row + r) * ldc + col] = acc[i][j][r];
      }
    }
  }
}

// ---------------- RoPE ----------------
__global__ __launch_bounds__(256) void rope_kernel(
    const u16* __restrict__ src, u16* __restrict__ dst,
    const int* __restrict__ pos_ids, int nh, int src_col0, int dst_ld, int total,
    float scale) {
  int idx = blockIdx.x * 256 + threadIdx.x;
  if (idx >= total) return;
  int i = idx & 63;
  int t = idx >> 6;
  int hh = t % nh;
  int m = t / nh;
  float pos = (float)pos_ids[m];
  float inv = exp2f(-(float)i * 0.20762050593046016f);
  float f = pos * inv;
  float c = cosf(f) * scale, s = sinf(f) * scale;
  const u16* sp = src + (size_t)m * 6144 + src_col0 + hh * 128;
  float x0 = bf2f(sp[i]);
  float x1 = bf2f(sp[i + 64]);
  u16* dp = dst + (size_t)m * dst_ld + hh * 128;
  dp[i] = f2bf(x0 * c - x1 * s);
  dp[i + 64] = f2bf(x1 * c + x0 * s);
}

// ---------------- V transpose ----------------
__global__ __launch_bounds__(256) void vt_kernel(
    const u16* __restrict__ src, u16* __restrict__ vt) {
  __shared__ u16 tile[32][33];
  int s0 = blockIdx.x * 32;
  int d0 = blockIdx.y * 32;
  int bz = blockIdx.z;
  int b = bz >> 3, kvh = bz & 7;
  int tx = threadIdx.x, ty = threadIdx.y;
#pragma unroll
  for (int j = 0; j < 4; ++j)
    tile[ty + j * 8][tx] =
        src[(size_t)(b * 2048 + s0 + ty + j * 8) * 6144 + 5120 + kvh * 128 + d0 + tx];
  __syncthreads();
#pragma unroll
  for (int j = 0; j < 4; ++j)
    vt[((size_t)(b * 8 + kvh) * 128 + d0 + ty + j * 8) * 2048 + s0 + tx] =
        tile[tx][ty + j * 8];
}

// ---------------- Flash attention (causal, GQA), transposed S/O, XOR-swizzled LDS ----
#define PS_LD 76
__global__ __launch_bounds__(256, 3) void flash_kernel(
    const u16* __restrict__ Q, const u16* __restrict__ K,
    const u16* __restrict__ Vt, u16* __restrict__ O) {
  __shared__ alignas(16) u16 Ks[64 * 128];     // [kv][d] swizzled
  __shared__ alignas(16) u16 Vs[128 * 64];     // [d][kv] swizzled
  __shared__ alignas(16) u16 Ps[4][32 * PS_LD];

  const int tid = threadIdx.x;
  const int w = tid >> 6, lane = tid & 63;
  const int lq = lane & 15, qd = lane >> 4;
  const int lq7 = lq & 7;
  const int bh = blockIdx.y;
  const int b = bh >> 5, h = bh & 31, kvh = h >> 2;
  const int q0 = (gridDim.x - 1 - blockIdx.x) * 128;

  short8 qf[2][4];
  {
    const u16* qp = Q + ((size_t)(b * 2048 + q0 + w * 32 + lq) * 4096 + h * 128 + qd * 8);
#pragma unroll
    for (int n = 0; n < 2; ++n)
#pragma unroll
      for (int ks = 0; ks < 4; ++ks)
        qf[n][ks] = *(const short8*)(qp + (size_t)n * 16 * 4096 + ks * 32);
  }

  f32x4 ot[2][8] = {};
  float mprev[2], lsum[2];
#pragma unroll
  for (int n = 0; n < 2; ++n) { mprev[n] = -1e30f; lsum[n] = 0.f; }

  const int rk = lane >> 4;
  const int pk = lane & 15;
  const int ckA = (pk ^ rk) * 8;
  const int ckB = (pk ^ (4 + rk)) * 8;
  const int rv = lane >> 3;
  const int cv = ((lane & 7) ^ rv) * 8;

  const int kv_end = q0 + 128;

  for (int kv0 = 0; kv0 < kv_end; kv0 += 64) {
    {
      const u16* kbase = K + ((size_t)(b * 2048 + kv0 + w * 16 + rk) * 1024) + kvh * 128;
#pragma unroll
      for (int i = 0; i < 4; ++i)
        gl2lds16(kbase + (size_t)(i * 4) * 1024 + ((i & 1) ? ckB : ckA),
                 &Ks[(w * 16 + i * 4) * 128]);
      const u16* vbase = Vt + ((size_t)((b * 8 + kvh) * 128 + w * 32 + rv) * 2048) + kv0 + cv;
#pragma unroll
      for (int i = 0; i < 4; ++i)
        gl2lds16(vbase + (size_t)(i * 8) * 2048, &Vs[(w * 32 + i * 8) * 64]);
    }
    __syncthreads();

    f32x4 st[4][2] = {};
#pragma unroll
    for (int ks = 0; ks < 4; ++ks) {
      short8 kf[4];
#pragma unroll
      for (int m = 0; m < 4; ++m)
        kf[m] = *(const short8*)&Ks[(m * 16 + lq) * 128 + ((ks * 4 + qd) ^ lq7) * 8];
#pragma unroll
      for (int m = 0; m < 4; ++m)
#pragma unroll
        for (int n = 0; n < 2; ++n)
          st[m][n] = mfma_bf16(kf[m], qf[n][ks], st[m][n]);
    }

    if (kv0 + 63 > q0) {
#pragma unroll
      for (int n = 0; n < 2; ++n) {
        const int qrow = q0 + w * 32 + n * 16 + lq;
#pragma unroll
        for (int m = 0; m < 4; ++m) {
          const int kvb = kv0 + m * 16 + qd * 4;
#pragma unroll
          for (int r = 0; r < 4; ++r)
            if (kvb + r > qrow) st[m][n][r] = -1e30f;
        }
      }
    }

#pragma unroll
    for (int n = 0; n < 2; ++n) {
      float t = st[0][n][0];
#pragma unroll
      for (int m = 0; m < 4; ++m)
#pragma unroll
        for (int r = 0; r < 4; ++r) t = fmaxf(t, st[m][n][r]);
      t = fmaxf(t, __shfl_xor(t, 16));
      t = fmaxf(t, __shfl_xor(t, 32));
      const float mnew = fmaxf(mprev[n], t);
      const float alpha = __expf(mprev[n] - mnew);
      mprev[n] = mnew;

      float rs = 0.f;
      u32 pk2[4][2];
#pragma unroll
      for (int m = 0; m < 4; ++m) {
        float p0 = __expf(st[m][n][0] - mnew);
        float p1 = __expf(st[m][n][1] - mnew);
        float p2 = __expf(st[m][n][2] - mnew);
        float p3 = __expf(st[m][n][3] - mnew);
        rs += (p0 + p1) + (p2 + p3);
        pk2[m][0] = pack_bf2(p0, p1);
        pk2[m][1] = pack_bf2(p2, p3);
      }
      rs += __shfl_xor(rs, 16);
      rs += __shfl_xor(rs, 32);
      lsum[n] = lsum[n] * alpha + rs;

      u16* pw = &Ps[w][(n * 16 + lq) * PS_LD + qd * 4];
#pragma unroll
      for (int m = 0; m < 4; ++m)
        *(uint2*)(pw + m * 16) = make_uint2(pk2[m][0], pk2[m][1]);

#pragma unroll
      for (int mt = 0; mt < 8; ++mt)
#pragma unroll
        for (int r = 0; r < 4; ++r) ot[n][mt][r] *= alpha;
    }

#pragma unroll
    for (int kst = 0; kst < 2; ++kst) {
      short8 bp[2];
#pragma unroll
      for (int n = 0; n < 2; ++n)
        bp[n] = *(const short8*)&Ps[w][(n * 16 + lq) * PS_LD + kst * 32 + qd * 8];
#pragma unroll
      for (int mt = 0; mt < 8; ++mt) {
        short8 av = *(const short8*)&Vs[(mt * 16 + lq) * 64 + ((kst * 4 + qd) ^ lq7) * 8];
#pragma unroll
        for (int n = 0; n < 2; ++n)
          ot[n][mt] = mfma_bf16(av, bp[n], ot[n][mt]);
      }
    }
    __syncthreads();
  }

#pragma unroll
  for (int n = 0; n < 2; ++n) {
    const float inv = 1.f / lsum[n];
    const size_t row = (size_t)(b * 2048 + q0 + w * 32 + n * 16 + lq);
    u16* op = O + row * 4096 + h * 128 + qd * 4;
#pragma unroll
    for (int mt = 0; mt < 8; ++mt) {
      u32 a = pack_bf2(ot[n][mt][0] * inv, ot[n][mt][1] * inv);
      u32 c = pack_bf2(ot[n][mt][2] * inv, ot[n][mt][3] * inv);
      *(uint2*)(op + mt * 16) = make_uint2(a, c);
    }
  }
}

// ---------------- launcher ----------------
extern "C" void kernel_launch(void* const* d_in, const int* in_sizes, int n_in,
                              void* d_out, int out_size, void* d_ws, size_t ws_size,
                              hipStream_t stream) {
  const float* hidden = (const float*)d_in[0];
  const int* pos = (const int*)d_in[1];
  const float* Wq = (const float*)d_in[2];
  const float* Wk = (const float*)d_in[3];
  const float* Wv = (const float*)d_in[4];
  const float* Wo = (const float*)d_in[5];
  float* out = (float*)d_out;

  char* ws = (char*)d_ws;
  u16* hbf   = (u16*)(ws);                       // 4096x4096 bf16     (32 MiB)
  u16* wqkvt = (u16*)(ws + 33554432ull);         // 6144x4096 bf16 B^T (48 MiB)
  u16* wot   = (u16*)(ws + 83886080ull);         // 4096x4096 bf16 B^T (32 MiB)
  u16* qkvbf = (u16*)(ws + 117440512ull);        // 4096x6144 bf16     (48 MiB)
  u16* qbf   = (u16*)(ws + 167772160ull);        // 4096x4096 bf16
  u16* kbf   = (u16*)(ws + 201326592ull);        // 4096x1024 bf16
  u16* vt    = (u16*)(ws + 209715200ull);        // 2x8x128x2048 bf16
  u16* obf   = (u16*)(ws + 218103808ull);        // 4096x4096 bf16 (ends at 240 MiB)

  f32_to_bf16_kernel<<<16384, 256, 0, stream>>>(hidden, hbf, 16777216);
  transpose_w_kernel<<<dim3(128, 128), dim3(32, 8), 0, stream>>>(Wq, wqkvt, 4096, 4096);
  transpose_w_kernel<<<dim3(32, 128), dim3(32, 8), 0, stream>>>(Wk, wqkvt + (size_t)4096 * 4096, 4096, 1024);
  transpose_w_kernel<<<dim3(32, 128), dim3(32, 8), 0, stream>>>(Wv, wqkvt + (size_t)5120 * 4096, 4096, 1024);
  transpose_w_kernel<<<dim3(128, 128), dim3(32, 8), 0, stream>>>(Wo, wot, 4096, 4096);

  gemm_bt<true><<<dim3(48, 32), 256, 0, stream>>>(hbf, wqkvt, nullptr, qkvbf, 4096, 6144);

  rope_kernel<<<32768, 256, 0, stream>>>(qkvbf, qbf, pos, 32, 0, 4096, 8388608, 0.08838834764831845f);
  rope_kernel<<<8192, 256, 0, stream>>>(qkvbf, kbf, pos, 8, 4096, 1024, 2097152, 1.0f);

  vt_kernel<<<dim3(64, 4, 16), dim3(32, 8), 0, stream>>>(qkvbf, vt);

  flash_kernel<<<dim3(16, 64), 256, 0, stream>>>(qbf, kbf, vt, obf);

  gemm_bt<false><<<dim3(32, 32), 256, 0, stream>>>(obf, wot, out, nullptr, 4096, 4096);
}